// Round 8
// baseline (278.984 us; speedup 1.0000x reference)
//
#include <hip/hip_runtime.h>
#include <math.h>

constexpr int CIN      = 256;
constexpr int HW       = 16384;       // 128*128
constexpr int NMID     = 64;
constexpr int HWTILE   = 128;         // spatial positions per block (4 waves x 32)
constexpr int TILE_B   = 8192;        // padded A-tile image (80 rows x 80B)
constexpr int NORM_OFF = 512;         // mask (8*64) floats first
constexpr int K_OFF    = 75497984;    // 512 + 8*64*9*16384
constexpr int IDX_OFF  = 75497985;

typedef __attribute__((ext_vector_type(8))) short bf16x8;   // 8 bf16 = 4 VGPR
typedef __attribute__((ext_vector_type(4))) float f32x4;

__device__ __forceinline__ unsigned bf16_rne(float f) {
    unsigned u = __float_as_uint(f);
    return (u + 0x7fffu + ((u >> 16) & 1u)) >> 16;          // bf16 bits, RNE
}

// ---------------------------------------------------------------------------
// Repack W into MFMA A-fragment image, split bf16 hi/lo, with a row permutation
// chosen so each mid's 10 rows (score + 9 taps) land in ONE lane's D-fragments:
// D row-in-block = q*4+reg  =>  position p = (idx/4)*16 + q*4 + idx%4, where
// q = (mid&7)>>1, idx = (mid&1)*10 + j.  Tile (g*8+kc, part): 80 rows x 32 c.
__global__ __launch_bounds__(256) void prep_w(const float* __restrict__ Wm,
                                              char* __restrict__ ws)
{
    const int o = blockIdx.x;         // original W row 0..639
    const int c = threadIdx.x;        // 0..255
    int mid, j;
    if (o < NMID) { mid = o; j = 0; }
    else          { mid = (o - NMID) / 9; j = 1 + (o - NMID) % 9; }
    const int g  = mid >> 3, ml = mid & 7, q = ml >> 1, mi = ml & 1;
    const int idx = mi * 10 + j;
    const int p   = (idx >> 2) * 16 + q * 4 + (idx & 3);    // tile row 0..79
    const float w = Wm[(size_t)o * CIN + c];
    const unsigned hi = bf16_rne(w);
    const float    fl = w - __uint_as_float(hi << 16);
    const unsigned lo = bf16_rne(fl);
    const int kc = c >> 5, cc = c & 31;
    char* base = ws + (size_t)((g * 8 + kc) * 2) * TILE_B + p * 80 + cc * 2;
    *(unsigned short*)(base)          = (unsigned short)hi;
    *(unsigned short*)(base + TILE_B) = (unsigned short)lo;
}

// ---------------------------------------------------------------------------
__global__ __launch_bounds__(512) void zero_mask_kernel(float* __restrict__ out) {
    out[threadIdx.x] = 0.0f;
}

// ---------------------------------------------------------------------------
// Split-bf16 MFMA GEMM (640x256 @ 256x128-tile) + lane-local softmax epilogue.
// Barrier-free; A-fragments stream from the 1 MB L2-resident W image through a
// REGISTER double-buffer (prefetch k+1 before computing k), and the 30-MFMA
// cluster is issued as 3 passes of 10 independent MFMAs (no same-acc chains).
__global__ __launch_bounds__(256, 2) void fused_main(const float* __restrict__ x,
                                                     const char* __restrict__ wimg,
                                                     const float* __restrict__ bvec,
                                                     float* __restrict__ out)
{
    const int tid  = threadIdx.x;
    const int wave = tid >> 6, lane = tid & 63;
    const int q    = lane >> 4, m = lane & 15;
    const int b    = blockIdx.x >> 7;
    const int hw0  = (blockIdx.x & 127) * HWTILE;

    // ---- B fragments: x[c][hw], lane holds 8 consecutive c; split hi/lo ----
    bf16x8 Bhi[2][8], Blo[2][8];
    const float* xb = x + (size_t)b * CIN * HW + hw0 + wave * 32 + m;
    #pragma unroll
    for (int t = 0; t < 2; ++t)
        #pragma unroll
        for (int kc = 0; kc < 8; ++kc) {
            float f[8];
            #pragma unroll
            for (int i = 0; i < 8; ++i)
                f[i] = xb[t * 16 + (size_t)(kc * 32 + q * 8 + i) * HW];
            union { unsigned u[4]; bf16x8 v; } uh, ul;
            #pragma unroll
            for (int jj = 0; jj < 4; ++jj) {
                const unsigned h0 = bf16_rne(f[2*jj]), h1 = bf16_rne(f[2*jj+1]);
                const float r0 = f[2*jj]   - __uint_as_float(h0 << 16);
                const float r1 = f[2*jj+1] - __uint_as_float(h1 << 16);
                uh.u[jj] = h0 | (h1 << 16);
                ul.u[jj] = bf16_rne(r0) | (bf16_rne(r1) << 16);
            }
            Bhi[t][kc] = uh.v; Blo[t][kc] = ul.v;
        }

    const char* aptr = wimg + m * 80 + q * 16;   // per-lane A base
    const float* bv9 = bvec + NMID;

    bf16x8 Ah[2][5], Al[2][5];                   // register double-buffer
#define LOADA(buf, tile) do {                                                  \
    const char* _ap = aptr + (size_t)(tile) * 2 * TILE_B;                      \
    _Pragma("unroll")                                                          \
    for (int _ot = 0; _ot < 5; ++_ot) {                                        \
        Ah[buf][_ot] = *(const bf16x8*)(_ap + _ot * 1280);                     \
        Al[buf][_ot] = *(const bf16x8*)(_ap + TILE_B + _ot * 1280);            \
    }                                                                          \
} while (0)

    LOADA(0, 0);
    #pragma unroll 1
    for (int g = 0; g < 8; ++g) {
        f32x4 acc[5][2];
        #pragma unroll
        for (int ot = 0; ot < 5; ++ot)
            #pragma unroll
            for (int t = 0; t < 2; ++t) acc[ot][t] = (f32x4){0.f, 0.f, 0.f, 0.f};

        #pragma unroll
        for (int kc = 0; kc < 8; ++kc) {
            const int cb = kc & 1;
            if (kc < 7)     LOADA(cb ^ 1, g * 8 + kc + 1);   // prefetch next step
            else if (g < 7) LOADA(cb ^ 1, (g + 1) * 8);      // across g-boundary

            __builtin_amdgcn_s_setprio(1);
            // pass 1: Ah*Bh  (10 independent MFMAs)
            #pragma unroll
            for (int ot = 0; ot < 5; ++ot)
                #pragma unroll
                for (int t2 = 0; t2 < 2; ++t2)
                    acc[ot][t2] = __builtin_amdgcn_mfma_f32_16x16x32_bf16(Ah[cb][ot], Bhi[t2][kc], acc[ot][t2], 0, 0, 0);
            // pass 2: Ah*Bl
            #pragma unroll
            for (int ot = 0; ot < 5; ++ot)
                #pragma unroll
                for (int t2 = 0; t2 < 2; ++t2)
                    acc[ot][t2] = __builtin_amdgcn_mfma_f32_16x16x32_bf16(Ah[cb][ot], Blo[t2][kc], acc[ot][t2], 0, 0, 0);
            // pass 3: Al*Bh
            #pragma unroll
            for (int ot = 0; ot < 5; ++ot)
                #pragma unroll
                for (int t2 = 0; t2 < 2; ++t2)
                    acc[ot][t2] = __builtin_amdgcn_mfma_f32_16x16x32_bf16(Al[cb][ot], Bhi[t2][kc], acc[ot][t2], 0, 0, 0);
            __builtin_amdgcn_s_setprio(0);
        }

        // ---- lane-local epilogue: lane owns mids q*2+mi at hw wave*32+t2*16+m.
        //      raw(idx) = acc[idx>>2][t2][idx&3]. Biases straight from L1.
        #pragma unroll
        for (int mi = 0; mi < 2; ++mi) {
            const int gmid = g * 8 + q * 2 + mi;
            const int i0 = mi * 10;
            float s = acc[i0 >> 2][0][i0 & 3] + acc[i0 >> 2][1][i0 & 3];
            s += __shfl_xor(s, 1); s += __shfl_xor(s, 2);
            s += __shfl_xor(s, 4); s += __shfl_xor(s, 8);
            if (m == 0) atomicAdd(&out[b * NMID + gmid], s);
            float bj[9];
            #pragma unroll
            for (int jj = 0; jj < 9; ++jj) bj[jj] = bv9[gmid * 9 + jj];
            #pragma unroll
            for (int t2 = 0; t2 < 2; ++t2) {
                float p[9];
                #pragma unroll
                for (int jj = 0; jj < 9; ++jj) {
                    const int idx = i0 + 1 + jj;
                    p[jj] = acc[idx >> 2][t2][idx & 3] + bj[jj];
                }
                float mx = p[0];
                #pragma unroll
                for (int jj = 1; jj < 9; ++jj) mx = fmaxf(mx, p[jj]);
                float ss = 0.f;
                #pragma unroll
                for (int jj = 0; jj < 9; ++jj) { p[jj] = __expf(p[jj] - mx); ss += p[jj]; }
                const float rs = 1.0f / ss;
                float* ob = out + NORM_OFF
                          + ((size_t)((b * NMID + gmid) * 9)) * HW
                          + hw0 + wave * 32 + t2 * 16 + m;
                #pragma unroll
                for (int jj = 0; jj < 9; ++jj)
                    ob[(size_t)jj * HW] = p[jj] * rs;
            }
        }
    }
#undef LOADA
}

// ---------------------------------------------------------------------------
// One block, 8 waves; wave b handles batch b. Sigmoid of means (+score bias),
// stable top-k (desc value, tie -> lower index), mask, k, indices.
__global__ __launch_bounds__(512) void finalize_kernel(float* __restrict__ out,
                                                       const float* __restrict__ bvec,
                                                       int k)
{
    const int tid  = threadIdx.x;
    const int b    = tid >> 6;
    const int lane = tid & 63;
    const float sum = out[b * NMID + lane];
    const float sv  = 1.0f / (1.0f + __expf(-(sum * (1.0f / 16384.0f) + bvec[lane])));
    float val      = sv;
    float selected = 0.0f;
    for (int t = 0; t < k; ++t) {
        float bvv = val;
        int   bi  = lane;
        #pragma unroll
        for (int off = 32; off >= 1; off >>= 1) {
            const float ov = __shfl_xor(bvv, off);
            const int   oi = __shfl_xor(bi, off);
            if (ov > bvv || (ov == bvv && oi < bi)) { bvv = ov; bi = oi; }
        }
        if (lane == bi) { val = -INFINITY; selected = 1.0f; }
        if (lane == 0) out[IDX_OFF + b * k + t] = (float)bi;
    }
    out[b * NMID + lane] = selected;            // overwrite sums with mask
    if (tid == 0) out[K_OFF] = (float)k;
}

// ---------------------------------------------------------------------------
extern "C" void kernel_launch(void* const* d_in, const int* in_sizes, int n_in,
                              void* d_out, int out_size, void* d_ws, size_t ws_size,
                              hipStream_t stream)
{
    const float* x    = (const float*)d_in[0];
    const float* Wm   = (const float*)d_in[1];
    const float* bvec = (const float*)d_in[2];
    float* out = (float*)d_out;
    char*  ws  = (char*)d_ws;           // 64 tiles x 2 parts x 8192 B = 1 MB

    // out_size = 512 (mask) + 75497472 (norm_kernels) + 1 (k) + 8*k (indices)
    const int k = (out_size - IDX_OFF) / 8;

    prep_w<<<640, 256, 0, stream>>>(Wm, ws);
    zero_mask_kernel<<<1, 512, 0, stream>>>(out);
    fused_main<<<8 * (HW / HWTILE), 256, 0, stream>>>(x, ws, bvec, out);
    finalize_kernel<<<1, 512, 0, stream>>>(out, bvec, k);
}

// Round 9
// 210.807 us; speedup vs baseline: 1.3234x; 1.3234x over previous
//
#include <hip/hip_runtime.h>
#include <math.h>

constexpr int CIN      = 256;
constexpr int HW       = 16384;       // 128*128
constexpr int NMID     = 64;
constexpr int HWTILE   = 128;         // spatial positions per block (4 waves x 32)
constexpr int TILE_B   = 8192;        // padded A-tile image (80 rows x 80B)
constexpr int NORM_OFF = 512;         // mask (8*64) floats first
constexpr int K_OFF    = 75497984;    // 512 + 8*64*9*16384
constexpr int IDX_OFF  = 75497985;

typedef __attribute__((ext_vector_type(8))) short bf16x8;   // 8 bf16 = 4 VGPR
typedef __attribute__((ext_vector_type(4))) float f32x4;

__device__ __forceinline__ unsigned bf16_rne(float f) {
    unsigned u = __float_as_uint(f);
    return (u + 0x7fffu + ((u >> 16) & 1u)) >> 16;          // bf16 bits, RNE
}

// ---------------------------------------------------------------------------
// Repack W into MFMA A-fragment image, split bf16 hi/lo, with a row permutation
// chosen so each mid's 10 rows (score + 9 taps) land in ONE lane's D-fragments:
// D row-in-block = q*4+reg  =>  position p = (idx/4)*16 + q*4 + idx%4, where
// q = (mid&7)>>1, idx = (mid&1)*10 + j.  Tile (g*8+kc, part): 80 rows x 32 c.
__global__ __launch_bounds__(256) void prep_w(const float* __restrict__ Wm,
                                              char* __restrict__ ws)
{
    const int o = blockIdx.x;         // original W row 0..639
    const int c = threadIdx.x;        // 0..255
    int mid, j;
    if (o < NMID) { mid = o; j = 0; }
    else          { mid = (o - NMID) / 9; j = 1 + (o - NMID) % 9; }
    const int g  = mid >> 3, ml = mid & 7, q = ml >> 1, mi = ml & 1;
    const int idx = mi * 10 + j;
    const int p   = (idx >> 2) * 16 + q * 4 + (idx & 3);    // tile row 0..79
    const float w = Wm[(size_t)o * CIN + c];
    const unsigned hi = bf16_rne(w);
    const float    fl = w - __uint_as_float(hi << 16);
    const unsigned lo = bf16_rne(fl);
    const int kc = c >> 5, cc = c & 31;
    char* base = ws + (size_t)((g * 8 + kc) * 2) * TILE_B + p * 80 + cc * 2;
    *(unsigned short*)(base)          = (unsigned short)hi;
    *(unsigned short*)(base + TILE_B) = (unsigned short)lo;
}

// ---------------------------------------------------------------------------
__global__ __launch_bounds__(512) void zero_mask_kernel(float* __restrict__ out) {
    out[threadIdx.x] = 0.0f;
}

// ---------------------------------------------------------------------------
// Split-bf16 MFMA GEMM (640x256 @ 256x128-tile) + lane-local softmax epilogue.
// Barrier-free, A direct from the 1 MB L2-resident W image (round-7 structure).
// NEW: per-block g-phase rotation — without it, every block machine-wide reads
// the SAME 16 KB A-tile simultaneously, serializing on ~128 hot L2 lines.
// Rotation spreads the instantaneous hot set across 8 g-slices (bid>>3 so
// blocks sharing an XCD/L2 get different phases).
__global__ __launch_bounds__(256, 2) void fused_main(const float* __restrict__ x,
                                                     const char* __restrict__ wimg,
                                                     const float* __restrict__ bvec,
                                                     float* __restrict__ out)
{
    const int tid  = threadIdx.x;
    const int wave = tid >> 6, lane = tid & 63;
    const int q    = lane >> 4, m = lane & 15;
    const int b    = blockIdx.x >> 7;
    const int hw0  = (blockIdx.x & 127) * HWTILE;
    const int grot = (blockIdx.x >> 3) & 7;      // g-phase rotation

    // ---- B fragments: x[c][hw], lane holds 8 consecutive c; split hi/lo ----
    bf16x8 Bhi[2][8], Blo[2][8];
    const float* xb = x + (size_t)b * CIN * HW + hw0 + wave * 32 + m;
    #pragma unroll
    for (int t = 0; t < 2; ++t)
        #pragma unroll
        for (int kc = 0; kc < 8; ++kc) {
            float f[8];
            #pragma unroll
            for (int i = 0; i < 8; ++i)
                f[i] = xb[t * 16 + (size_t)(kc * 32 + q * 8 + i) * HW];
            union { unsigned u[4]; bf16x8 v; } uh, ul;
            #pragma unroll
            for (int jj = 0; jj < 4; ++jj) {
                const unsigned h0 = bf16_rne(f[2*jj]), h1 = bf16_rne(f[2*jj+1]);
                const float r0 = f[2*jj]   - __uint_as_float(h0 << 16);
                const float r1 = f[2*jj+1] - __uint_as_float(h1 << 16);
                uh.u[jj] = h0 | (h1 << 16);
                ul.u[jj] = bf16_rne(r0) | (bf16_rne(r1) << 16);
            }
            Bhi[t][kc] = uh.v; Blo[t][kc] = ul.v;
        }

    const char* aptr = wimg + m * 80 + q * 16;   // per-lane A base
    const float* bv9 = bvec + NMID;

    #pragma unroll 1
    for (int gg = 0; gg < 8; ++gg) {
        const int g = (gg + grot) & 7;           // rotated output-group index
        f32x4 acc[5][2];
        #pragma unroll
        for (int ot = 0; ot < 5; ++ot)
            #pragma unroll
            for (int t = 0; t < 2; ++t) acc[ot][t] = (f32x4){0.f, 0.f, 0.f, 0.f};

        #pragma unroll
        for (int kc = 0; kc < 8; ++kc) {
            const char* ap = aptr + (size_t)((g * 8 + kc) * 2) * TILE_B;
            bf16x8 Ah[5], Al[5];
            #pragma unroll
            for (int ot = 0; ot < 5; ++ot) {
                Ah[ot] = *(const bf16x8*)(ap + ot * 1280);
                Al[ot] = *(const bf16x8*)(ap + TILE_B + ot * 1280);
            }
            __builtin_amdgcn_s_setprio(1);
            #pragma unroll
            for (int ot = 0; ot < 5; ++ot) {
                #pragma unroll
                for (int t2 = 0; t2 < 2; ++t2) {
                    acc[ot][t2] = __builtin_amdgcn_mfma_f32_16x16x32_bf16(Ah[ot], Bhi[t2][kc], acc[ot][t2], 0, 0, 0);
                    acc[ot][t2] = __builtin_amdgcn_mfma_f32_16x16x32_bf16(Ah[ot], Blo[t2][kc], acc[ot][t2], 0, 0, 0);
                    acc[ot][t2] = __builtin_amdgcn_mfma_f32_16x16x32_bf16(Al[ot], Bhi[t2][kc], acc[ot][t2], 0, 0, 0);
                }
            }
            __builtin_amdgcn_s_setprio(0);
        }

        // ---- lane-local epilogue: lane owns mids q*2+mi at hw wave*32+t2*16+m.
        //      raw(idx) = acc[idx>>2][t2][idx&3]. Biases straight from L1.
        #pragma unroll
        for (int mi = 0; mi < 2; ++mi) {
            const int gmid = g * 8 + q * 2 + mi;
            const int i0 = mi * 10;
            float s = acc[i0 >> 2][0][i0 & 3] + acc[i0 >> 2][1][i0 & 3];
            s += __shfl_xor(s, 1); s += __shfl_xor(s, 2);
            s += __shfl_xor(s, 4); s += __shfl_xor(s, 8);
            if (m == 0) atomicAdd(&out[b * NMID + gmid], s);
            float bj[9];
            #pragma unroll
            for (int jj = 0; jj < 9; ++jj) bj[jj] = bv9[gmid * 9 + jj];
            #pragma unroll
            for (int t2 = 0; t2 < 2; ++t2) {
                float p[9];
                #pragma unroll
                for (int jj = 0; jj < 9; ++jj) {
                    const int idx = i0 + 1 + jj;
                    p[jj] = acc[idx >> 2][t2][idx & 3] + bj[jj];
                }
                float mx = p[0];
                #pragma unroll
                for (int jj = 1; jj < 9; ++jj) mx = fmaxf(mx, p[jj]);
                float ss = 0.f;
                #pragma unroll
                for (int jj = 0; jj < 9; ++jj) { p[jj] = __expf(p[jj] - mx); ss += p[jj]; }
                const float rs = 1.0f / ss;
                float* ob = out + NORM_OFF
                          + ((size_t)((b * NMID + gmid) * 9)) * HW
                          + hw0 + wave * 32 + t2 * 16 + m;
                #pragma unroll
                for (int jj = 0; jj < 9; ++jj)
                    ob[(size_t)jj * HW] = p[jj] * rs;
            }
        }
    }
}

// ---------------------------------------------------------------------------
// One block, 8 waves; wave b handles batch b. Sigmoid of means (+score bias),
// stable top-k (desc value, tie -> lower index), mask, k, indices.
__global__ __launch_bounds__(512) void finalize_kernel(float* __restrict__ out,
                                                       const float* __restrict__ bvec,
                                                       int k)
{
    const int tid  = threadIdx.x;
    const int b    = tid >> 6;
    const int lane = tid & 63;
    const float sum = out[b * NMID + lane];
    const float sv  = 1.0f / (1.0f + __expf(-(sum * (1.0f / 16384.0f) + bvec[lane])));
    float val      = sv;
    float selected = 0.0f;
    for (int t = 0; t < k; ++t) {
        float bvv = val;
        int   bi  = lane;
        #pragma unroll
        for (int off = 32; off >= 1; off >>= 1) {
            const float ov = __shfl_xor(bvv, off);
            const int   oi = __shfl_xor(bi, off);
            if (ov > bvv || (ov == bvv && oi < bi)) { bvv = ov; bi = oi; }
        }
        if (lane == bi) { val = -INFINITY; selected = 1.0f; }
        if (lane == 0) out[IDX_OFF + b * k + t] = (float)bi;
    }
    out[b * NMID + lane] = selected;            // overwrite sums with mask
    if (tid == 0) out[K_OFF] = (float)k;
}

// ---------------------------------------------------------------------------
extern "C" void kernel_launch(void* const* d_in, const int* in_sizes, int n_in,
                              void* d_out, int out_size, void* d_ws, size_t ws_size,
                              hipStream_t stream)
{
    const float* x    = (const float*)d_in[0];
    const float* Wm   = (const float*)d_in[1];
    const float* bvec = (const float*)d_in[2];
    float* out = (float*)d_out;
    char*  ws  = (char*)d_ws;           // 64 tiles x 2 parts x 8192 B = 1 MB

    // out_size = 512 (mask) + 75497472 (norm_kernels) + 1 (k) + 8*k (indices)
    const int k = (out_size - IDX_OFF) / 8;

    prep_w<<<640, 256, 0, stream>>>(Wm, ws);
    zero_mask_kernel<<<1, 512, 0, stream>>>(out);
    fused_main<<<8 * (HW / HWTILE), 256, 0, stream>>>(x, ws, bvec, out);
    finalize_kernel<<<1, 512, 0, stream>>>(out, bvec, k);
}

// Round 10
// 195.624 us; speedup vs baseline: 1.4261x; 1.0776x over previous
//
#include <hip/hip_runtime.h>
#include <math.h>

constexpr int CIN      = 256;
constexpr int HW       = 16384;       // 128*128
constexpr int NMID     = 64;
constexpr int HWTILE   = 128;         // spatial positions per block (4 waves x 32)
constexpr int TILE_B   = 8192;        // padded A-tile image (80 rows x 80B)
constexpr int NORM_OFF = 512;         // mask (8*64) floats first
constexpr int K_OFF    = 75497984;    // 512 + 8*64*9*16384
constexpr int IDX_OFF  = 75497985;

typedef __attribute__((ext_vector_type(8))) short bf16x8;   // 8 bf16 = 4 VGPR
typedef __attribute__((ext_vector_type(4))) float f32x4;

__device__ __forceinline__ unsigned bf16_rne(float f) {
    unsigned u = __float_as_uint(f);
    return (u + 0x7fffu + ((u >> 16) & 1u)) >> 16;          // bf16 bits, RNE
}

// ---------------------------------------------------------------------------
// Repack W into MFMA A-fragment image, split bf16 hi/lo, with a row permutation
// chosen so each mid's 10 rows (score + 9 taps) land in ONE lane's D-fragments:
// D row-in-block = q*4+reg  =>  position p = (idx/4)*16 + q*4 + idx%4, where
// q = (mid&7)>>1, idx = (mid&1)*10 + j.  Tile (g*8+kc, part): 80 rows x 32 c.
__global__ __launch_bounds__(256) void prep_w(const float* __restrict__ Wm,
                                              char* __restrict__ ws)
{
    const int o = blockIdx.x;         // original W row 0..639
    const int c = threadIdx.x;        // 0..255
    int mid, j;
    if (o < NMID) { mid = o; j = 0; }
    else          { mid = (o - NMID) / 9; j = 1 + (o - NMID) % 9; }
    const int g  = mid >> 3, ml = mid & 7, q = ml >> 1, mi = ml & 1;
    const int idx = mi * 10 + j;
    const int p   = (idx >> 2) * 16 + q * 4 + (idx & 3);    // tile row 0..79
    const float w = Wm[(size_t)o * CIN + c];
    const unsigned hi = bf16_rne(w);
    const float    fl = w - __uint_as_float(hi << 16);
    const unsigned lo = bf16_rne(fl);
    const int kc = c >> 5, cc = c & 31;
    char* base = ws + (size_t)((g * 8 + kc) * 2) * TILE_B + p * 80 + cc * 2;
    *(unsigned short*)(base)          = (unsigned short)hi;
    *(unsigned short*)(base + TILE_B) = (unsigned short)lo;
}

// ---------------------------------------------------------------------------
__global__ __launch_bounds__(512) void zero_mask_kernel(float* __restrict__ out) {
    out[threadIdx.x] = 0.0f;
}

// ---------------------------------------------------------------------------
// Split-bf16 MFMA GEMM (640x256 @ 256x128-tile) + lane-local softmax epilogue.
// Barrier-free, A direct from the 1 MB L2-resident W image, per-block g-phase
// rotation (round-9). NEW vs r9:
//  (1) MFMA cluster emitted as 3 passes of 10 INDEPENDENT MFMAs (no same-acc
//      back-to-back chains; same-acc reuse separated by ~48 issue cycles).
//  (2) norm_kernels stores are nontemporal: the 302 MB write stream no longer
//      evicts the W-image from L2.
__global__ __launch_bounds__(256, 2) void fused_main(const float* __restrict__ x,
                                                     const char* __restrict__ wimg,
                                                     const float* __restrict__ bvec,
                                                     float* __restrict__ out)
{
    const int tid  = threadIdx.x;
    const int wave = tid >> 6, lane = tid & 63;
    const int q    = lane >> 4, m = lane & 15;
    const int b    = blockIdx.x >> 7;
    const int hw0  = (blockIdx.x & 127) * HWTILE;
    const int grot = (blockIdx.x >> 3) & 7;      // g-phase rotation

    // ---- B fragments: x[c][hw], lane holds 8 consecutive c; split hi/lo ----
    bf16x8 Bhi[2][8], Blo[2][8];
    const float* xb = x + (size_t)b * CIN * HW + hw0 + wave * 32 + m;
    #pragma unroll
    for (int t = 0; t < 2; ++t)
        #pragma unroll
        for (int kc = 0; kc < 8; ++kc) {
            float f[8];
            #pragma unroll
            for (int i = 0; i < 8; ++i)
                f[i] = xb[t * 16 + (size_t)(kc * 32 + q * 8 + i) * HW];
            union { unsigned u[4]; bf16x8 v; } uh, ul;
            #pragma unroll
            for (int jj = 0; jj < 4; ++jj) {
                const unsigned h0 = bf16_rne(f[2*jj]), h1 = bf16_rne(f[2*jj+1]);
                const float r0 = f[2*jj]   - __uint_as_float(h0 << 16);
                const float r1 = f[2*jj+1] - __uint_as_float(h1 << 16);
                uh.u[jj] = h0 | (h1 << 16);
                ul.u[jj] = bf16_rne(r0) | (bf16_rne(r1) << 16);
            }
            Bhi[t][kc] = uh.v; Blo[t][kc] = ul.v;
        }

    const char* aptr = wimg + m * 80 + q * 16;   // per-lane A base
    const float* bv9 = bvec + NMID;

    #pragma unroll 1
    for (int gg = 0; gg < 8; ++gg) {
        const int g = (gg + grot) & 7;           // rotated output-group index
        f32x4 acc[5][2];
        #pragma unroll
        for (int ot = 0; ot < 5; ++ot)
            #pragma unroll
            for (int t = 0; t < 2; ++t) acc[ot][t] = (f32x4){0.f, 0.f, 0.f, 0.f};

        #pragma unroll
        for (int kc = 0; kc < 8; ++kc) {
            const char* ap = aptr + (size_t)((g * 8 + kc) * 2) * TILE_B;
            bf16x8 Ah[5], Al[5];
            #pragma unroll
            for (int ot = 0; ot < 5; ++ot) {
                Ah[ot] = *(const bf16x8*)(ap + ot * 1280);
                Al[ot] = *(const bf16x8*)(ap + TILE_B + ot * 1280);
            }
            __builtin_amdgcn_s_setprio(1);
            // pass 1: Ah*Bh — 10 independent MFMAs
            #pragma unroll
            for (int ot = 0; ot < 5; ++ot)
                #pragma unroll
                for (int t2 = 0; t2 < 2; ++t2)
                    acc[ot][t2] = __builtin_amdgcn_mfma_f32_16x16x32_bf16(Ah[ot], Bhi[t2][kc], acc[ot][t2], 0, 0, 0);
            // pass 2: Ah*Bl
            #pragma unroll
            for (int ot = 0; ot < 5; ++ot)
                #pragma unroll
                for (int t2 = 0; t2 < 2; ++t2)
                    acc[ot][t2] = __builtin_amdgcn_mfma_f32_16x16x32_bf16(Ah[ot], Blo[t2][kc], acc[ot][t2], 0, 0, 0);
            // pass 3: Al*Bh
            #pragma unroll
            for (int ot = 0; ot < 5; ++ot)
                #pragma unroll
                for (int t2 = 0; t2 < 2; ++t2)
                    acc[ot][t2] = __builtin_amdgcn_mfma_f32_16x16x32_bf16(Al[ot], Bhi[t2][kc], acc[ot][t2], 0, 0, 0);
            __builtin_amdgcn_s_setprio(0);
        }

        // ---- lane-local epilogue: lane owns mids q*2+mi at hw wave*32+t2*16+m.
        //      raw(idx) = acc[idx>>2][t2][idx&3]. Biases straight from L1.
        #pragma unroll
        for (int mi = 0; mi < 2; ++mi) {
            const int gmid = g * 8 + q * 2 + mi;
            const int i0 = mi * 10;
            float s = acc[i0 >> 2][0][i0 & 3] + acc[i0 >> 2][1][i0 & 3];
            s += __shfl_xor(s, 1); s += __shfl_xor(s, 2);
            s += __shfl_xor(s, 4); s += __shfl_xor(s, 8);
            if (m == 0) atomicAdd(&out[b * NMID + gmid], s);
            float bj[9];
            #pragma unroll
            for (int jj = 0; jj < 9; ++jj) bj[jj] = bv9[gmid * 9 + jj];
            #pragma unroll
            for (int t2 = 0; t2 < 2; ++t2) {
                float p[9];
                #pragma unroll
                for (int jj = 0; jj < 9; ++jj) {
                    const int idx = i0 + 1 + jj;
                    p[jj] = acc[idx >> 2][t2][idx & 3] + bj[jj];
                }
                float mx = p[0];
                #pragma unroll
                for (int jj = 1; jj < 9; ++jj) mx = fmaxf(mx, p[jj]);
                float ss = 0.f;
                #pragma unroll
                for (int jj = 0; jj < 9; ++jj) { p[jj] = __expf(p[jj] - mx); ss += p[jj]; }
                const float rs = 1.0f / ss;
                float* ob = out + NORM_OFF
                          + ((size_t)((b * NMID + gmid) * 9)) * HW
                          + hw0 + wave * 32 + t2 * 16 + m;
                #pragma unroll
                for (int jj = 0; jj < 9; ++jj)
                    __builtin_nontemporal_store(p[jj] * rs, ob + (size_t)jj * HW);
            }
        }
    }
}

// ---------------------------------------------------------------------------
// One block, 8 waves; wave b handles batch b. Sigmoid of means (+score bias),
// stable top-k (desc value, tie -> lower index), mask, k, indices.
__global__ __launch_bounds__(512) void finalize_kernel(float* __restrict__ out,
                                                       const float* __restrict__ bvec,
                                                       int k)
{
    const int tid  = threadIdx.x;
    const int b    = tid >> 6;
    const int lane = tid & 63;
    const float sum = out[b * NMID + lane];
    const float sv  = 1.0f / (1.0f + __expf(-(sum * (1.0f / 16384.0f) + bvec[lane])));
    float val      = sv;
    float selected = 0.0f;
    for (int t = 0; t < k; ++t) {
        float bvv = val;
        int   bi  = lane;
        #pragma unroll
        for (int off = 32; off >= 1; off >>= 1) {
            const float ov = __shfl_xor(bvv, off);
            const int   oi = __shfl_xor(bi, off);
            if (ov > bvv || (ov == bvv && oi < bi)) { bvv = ov; bi = oi; }
        }
        if (lane == bi) { val = -INFINITY; selected = 1.0f; }
        if (lane == 0) out[IDX_OFF + b * k + t] = (float)bi;
    }
    out[b * NMID + lane] = selected;            // overwrite sums with mask
    if (tid == 0) out[K_OFF] = (float)k;
}

// ---------------------------------------------------------------------------
extern "C" void kernel_launch(void* const* d_in, const int* in_sizes, int n_in,
                              void* d_out, int out_size, void* d_ws, size_t ws_size,
                              hipStream_t stream)
{
    const float* x    = (const float*)d_in[0];
    const float* Wm   = (const float*)d_in[1];
    const float* bvec = (const float*)d_in[2];
    float* out = (float*)d_out;
    char*  ws  = (char*)d_ws;           // 64 tiles x 2 parts x 8192 B = 1 MB

    // out_size = 512 (mask) + 75497472 (norm_kernels) + 1 (k) + 8*k (indices)
    const int k = (out_size - IDX_OFF) / 8;

    prep_w<<<640, 256, 0, stream>>>(Wm, ws);
    zero_mask_kernel<<<1, 512, 0, stream>>>(out);
    fused_main<<<8 * (HW / HWTILE), 256, 0, stream>>>(x, ws, bvec, out);
    finalize_kernel<<<1, 512, 0, stream>>>(out, bvec, k);
}

// Round 11
// 181.870 us; speedup vs baseline: 1.5340x; 1.0756x over previous
//
#include <hip/hip_runtime.h>
#include <math.h>

constexpr int CIN      = 256;
constexpr int HW       = 16384;       // 128*128
constexpr int NMID     = 64;
constexpr int HWTILE   = 128;         // spatial positions per block (4 waves x 32)
constexpr int TILE_B   = 8192;        // padded A-tile image (80 rows x 80B)
constexpr int NORM_OFF = 512;         // mask (8*64) floats first
constexpr int K_OFF    = 75497984;    // 512 + 8*64*9*16384
constexpr int IDX_OFF  = 75497985;

typedef __attribute__((ext_vector_type(8))) short bf16x8;   // 8 bf16 = 4 VGPR
typedef __attribute__((ext_vector_type(4))) float f32x4;

__device__ __forceinline__ unsigned bf16_rne(float f) {
    unsigned u = __float_as_uint(f);
    return (u + 0x7fffu + ((u >> 16) & 1u)) >> 16;          // bf16 bits, RNE
}

__device__ __forceinline__ void gload_lds16(const void* gsrc, void* ldst) {
    __builtin_amdgcn_global_load_lds(
        (const __attribute__((address_space(1))) void*)gsrc,
        (__attribute__((address_space(3))) void*)ldst, 16, 0, 0);
}

// ---------------------------------------------------------------------------
// Repack W into MFMA A-fragment image, split bf16 hi/lo, with a row permutation
// chosen so each mid's 10 rows (score + 9 taps) land in ONE lane's D-fragments:
// D row-in-block = q*4+reg  =>  position p = (idx/4)*16 + q*4 + idx%4, where
// q = (mid&7)>>1, idx = (mid&1)*10 + j.  Tile (g*8+kc, part): 80 rows x 32 c.
__global__ __launch_bounds__(256) void prep_w(const float* __restrict__ Wm,
                                              char* __restrict__ ws)
{
    const int o = blockIdx.x;         // original W row 0..639
    const int c = threadIdx.x;        // 0..255
    int mid, j;
    if (o < NMID) { mid = o; j = 0; }
    else          { mid = (o - NMID) / 9; j = 1 + (o - NMID) % 9; }
    const int g  = mid >> 3, ml = mid & 7, q = ml >> 1, mi = ml & 1;
    const int idx = mi * 10 + j;
    const int p   = (idx >> 2) * 16 + q * 4 + (idx & 3);    // tile row 0..79
    const float w = Wm[(size_t)o * CIN + c];
    const unsigned hi = bf16_rne(w);
    const float    fl = w - __uint_as_float(hi << 16);
    const unsigned lo = bf16_rne(fl);
    const int kc = c >> 5, cc = c & 31;
    char* base = ws + (size_t)((g * 8 + kc) * 2) * TILE_B + p * 80 + cc * 2;
    *(unsigned short*)(base)          = (unsigned short)hi;
    *(unsigned short*)(base + TILE_B) = (unsigned short)lo;
}

// ---------------------------------------------------------------------------
__global__ __launch_bounds__(512) void zero_mask_kernel(float* __restrict__ out) {
    out[threadIdx.x] = 0.0f;
}

// ---------------------------------------------------------------------------
// Split-bf16 MFMA GEMM (640x256 @ 256x128-tile) + lane-local softmax epilogue.
// A staged ONCE PER BLOCK into LDS (async gload_lds, 3 buffers, 2-step-ahead
// prefetch, FIFO-counted vmcnt), shared by 4 waves -> 4x less L2 demand than
// per-wave global reads. g-phase rotation vs L2 hot-tile contention. MFMA
// cluster de-chained (3 passes of 10 independent MFMAs). nt stores.
__global__ __launch_bounds__(256, 2) void fused_main(const float* __restrict__ x,
                                                     const char* __restrict__ wimg,
                                                     const float* __restrict__ bvec,
                                                     float* __restrict__ out)
{
    __shared__ __align__(16) char atile[3][2][TILE_B];   // 48 KB
    __shared__ float bsh[576];                           // tap biases

    const int tid  = threadIdx.x;
    const int wave = tid >> 6, lane = tid & 63;
    const int q    = lane >> 4, m = lane & 15;
    const int b    = blockIdx.x >> 7;
    const int hw0  = (blockIdx.x & 127) * HWTILE;
    const int grot = (blockIdx.x >> 3) & 7;      // g-phase rotation

#define STAGE(tile, buf) do {                                                  \
    const char* _s = wimg + (size_t)(tile) * 2 * TILE_B;                       \
    char* _d = &atile[buf][0][0];                                              \
    gload_lds16(_s + tid * 16,                 _d + tid * 16);                 \
    gload_lds16(_s + 4096 + tid * 16,          _d + 4096 + tid * 16);          \
    gload_lds16(_s + TILE_B + tid * 16,        _d + TILE_B + tid * 16);        \
    gload_lds16(_s + TILE_B + 4096 + tid * 16, _d + TILE_B + 4096 + tid * 16); \
} while (0)

    // tiles are consumed in rotated order; stage the first two now
    const int t0 = grot * 8;
    STAGE(t0, 0);
    STAGE(t0 + 1, 1);

    // ---- B fragments: x[c][hw], lane holds 8 consecutive c; split hi/lo ----
    // (these x-loads are younger than the stages in the VMEM FIFO; consuming
    //  them retires the stages in-order, so tile t0 is landed before use)
    bf16x8 Bhi[2][8], Blo[2][8];
    const float* xb = x + (size_t)b * CIN * HW + hw0 + wave * 32 + m;
    #pragma unroll
    for (int t = 0; t < 2; ++t)
        #pragma unroll
        for (int kc = 0; kc < 8; ++kc) {
            float f[8];
            #pragma unroll
            for (int i = 0; i < 8; ++i)
                f[i] = xb[t * 16 + (size_t)(kc * 32 + q * 8 + i) * HW];
            union { unsigned u[4]; bf16x8 v; } uh, ul;
            #pragma unroll
            for (int jj = 0; jj < 4; ++jj) {
                const unsigned h0 = bf16_rne(f[2*jj]), h1 = bf16_rne(f[2*jj+1]);
                const float r0 = f[2*jj]   - __uint_as_float(h0 << 16);
                const float r1 = f[2*jj+1] - __uint_as_float(h1 << 16);
                uh.u[jj] = h0 | (h1 << 16);
                ul.u[jj] = bf16_rne(r0) | (bf16_rne(r1) << 16);
            }
            Bhi[t][kc] = uh.v; Blo[t][kc] = ul.v;
        }
    for (int i = tid; i < 576; i += 256) bsh[i] = bvec[NMID + i];
    asm volatile("s_waitcnt lgkmcnt(0)" ::: "memory");
    __builtin_amdgcn_s_barrier();

    int cur = 0;                         // LDS buffer holding current tile
    #pragma unroll 1
    for (int gg = 0; gg < 8; ++gg) {
        const int g = (gg + grot) & 7;   // rotated output-group index
        f32x4 acc[5][2];
        #pragma unroll
        for (int ot = 0; ot < 5; ++ot)
            #pragma unroll
            for (int t = 0; t < 2; ++t) acc[ot][t] = (f32x4){0.f, 0.f, 0.f, 0.f};

        #pragma unroll
        for (int kc = 0; kc < 8; ++kc) {
            const int seq = gg * 8 + kc;             // consumption order 0..63
            const int nb  = (cur >= 1) ? cur - 1 : 2; // (cur+2)%3
            if (seq <= 61) {
                const int nseq = seq + 2;            // tile 2 ahead, rotated
                STAGE((((nseq >> 3) + grot) & 7) * 8 + (nseq & 7), nb);
            }
            // FIFO-counted waits (in-order retirement):
            //  steady pre-wait: [stage seq, seq+1, seq+2] (12) -> vmcnt(8)
            //  kc<2 after an epilogue (38 VMEM between stages) -> vmcnt(46)
            //  tail: seq=62 -> vmcnt(4); seq=63 -> vmcnt(0)
            if (gg == 7 && kc == 7)      asm volatile("s_waitcnt vmcnt(0)"  ::: "memory");
            else if (gg == 7 && kc == 6) asm volatile("s_waitcnt vmcnt(4)"  ::: "memory");
            else if (gg > 0 && kc < 2)   asm volatile("s_waitcnt vmcnt(46)" ::: "memory");
            else                         asm volatile("s_waitcnt vmcnt(8)"  ::: "memory");
            __builtin_amdgcn_s_barrier();

            const char* ahi = &atile[cur][0][m * 80 + q * 16];
            const char* alo = &atile[cur][1][m * 80 + q * 16];
            bf16x8 Ah[5], Al[5];
            #pragma unroll
            for (int ot = 0; ot < 5; ++ot) {
                Ah[ot] = *(const bf16x8*)(ahi + ot * 1280);
                Al[ot] = *(const bf16x8*)(alo + ot * 1280);
            }
            __builtin_amdgcn_s_setprio(1);
            #pragma unroll
            for (int ot = 0; ot < 5; ++ot)
                #pragma unroll
                for (int t2 = 0; t2 < 2; ++t2)
                    acc[ot][t2] = __builtin_amdgcn_mfma_f32_16x16x32_bf16(Ah[ot], Bhi[t2][kc], acc[ot][t2], 0, 0, 0);
            #pragma unroll
            for (int ot = 0; ot < 5; ++ot)
                #pragma unroll
                for (int t2 = 0; t2 < 2; ++t2)
                    acc[ot][t2] = __builtin_amdgcn_mfma_f32_16x16x32_bf16(Ah[ot], Blo[t2][kc], acc[ot][t2], 0, 0, 0);
            #pragma unroll
            for (int ot = 0; ot < 5; ++ot)
                #pragma unroll
                for (int t2 = 0; t2 < 2; ++t2)
                    acc[ot][t2] = __builtin_amdgcn_mfma_f32_16x16x32_bf16(Al[ot], Bhi[t2][kc], acc[ot][t2], 0, 0, 0);
            __builtin_amdgcn_s_setprio(0);

            // ---- epilogue at kc==7 (before the phase-end barrier):
            //      lane owns mids q*2+mi at hw = hw0 + wave*32 + t2*16 + m ----
            if (kc == 7) {
                #pragma unroll
                for (int mi = 0; mi < 2; ++mi) {
                    const int gmid = g * 8 + q * 2 + mi;
                    const int i0 = mi * 10;
                    float s = acc[i0 >> 2][0][i0 & 3] + acc[i0 >> 2][1][i0 & 3];
                    s += __shfl_xor(s, 1); s += __shfl_xor(s, 2);
                    s += __shfl_xor(s, 4); s += __shfl_xor(s, 8);
                    if (m == 0) atomicAdd(&out[b * NMID + gmid], s);
                    float bj[9];
                    #pragma unroll
                    for (int jj = 0; jj < 9; ++jj) bj[jj] = bsh[gmid * 9 + jj];
                    #pragma unroll
                    for (int t2 = 0; t2 < 2; ++t2) {
                        float p[9];
                        #pragma unroll
                        for (int jj = 0; jj < 9; ++jj) {
                            const int idx = i0 + 1 + jj;
                            p[jj] = acc[idx >> 2][t2][idx & 3] + bj[jj];
                        }
                        float mx = p[0];
                        #pragma unroll
                        for (int jj = 1; jj < 9; ++jj) mx = fmaxf(mx, p[jj]);
                        float ss = 0.f;
                        #pragma unroll
                        for (int jj = 0; jj < 9; ++jj) { p[jj] = __expf(p[jj] - mx); ss += p[jj]; }
                        const float rs = 1.0f / ss;
                        float* ob = out + NORM_OFF
                                  + ((size_t)((b * NMID + gmid) * 9)) * HW
                                  + hw0 + wave * 32 + t2 * 16 + m;
                        #pragma unroll
                        for (int jj = 0; jj < 9; ++jj)
                            __builtin_nontemporal_store(p[jj] * rs, ob + (size_t)jj * HW);
                    }
                }
            }
            asm volatile("s_waitcnt lgkmcnt(0)" ::: "memory");
            __builtin_amdgcn_s_barrier();
            cur = (cur == 2) ? 0 : cur + 1;
        }
    }
#undef STAGE
}

// ---------------------------------------------------------------------------
// One block, 8 waves; wave b handles batch b. Sigmoid of means (+score bias),
// stable top-k (desc value, tie -> lower index), mask, k, indices.
__global__ __launch_bounds__(512) void finalize_kernel(float* __restrict__ out,
                                                       const float* __restrict__ bvec,
                                                       int k)
{
    const int tid  = threadIdx.x;
    const int b    = tid >> 6;
    const int lane = tid & 63;
    const float sum = out[b * NMID + lane];
    const float sv  = 1.0f / (1.0f + __expf(-(sum * (1.0f / 16384.0f) + bvec[lane])));
    float val      = sv;
    float selected = 0.0f;
    for (int t = 0; t < k; ++t) {
        float bvv = val;
        int   bi  = lane;
        #pragma unroll
        for (int off = 32; off >= 1; off >>= 1) {
            const float ov = __shfl_xor(bvv, off);
            const int   oi = __shfl_xor(bi, off);
            if (ov > bvv || (ov == bvv && oi < bi)) { bvv = ov; bi = oi; }
        }
        if (lane == bi) { val = -INFINITY; selected = 1.0f; }
        if (lane == 0) out[IDX_OFF + b * k + t] = (float)bi;
    }
    out[b * NMID + lane] = selected;            // overwrite sums with mask
    if (tid == 0) out[K_OFF] = (float)k;
}

// ---------------------------------------------------------------------------
extern "C" void kernel_launch(void* const* d_in, const int* in_sizes, int n_in,
                              void* d_out, int out_size, void* d_ws, size_t ws_size,
                              hipStream_t stream)
{
    const float* x    = (const float*)d_in[0];
    const float* Wm   = (const float*)d_in[1];
    const float* bvec = (const float*)d_in[2];
    float* out = (float*)d_out;
    char*  ws  = (char*)d_ws;           // 64 tiles x 2 parts x 8192 B = 1 MB

    // out_size = 512 (mask) + 75497472 (norm_kernels) + 1 (k) + 8*k (indices)
    const int k = (out_size - IDX_OFF) / 8;

    prep_w<<<640, 256, 0, stream>>>(Wm, ws);
    zero_mask_kernel<<<1, 512, 0, stream>>>(out);
    fused_main<<<8 * (HW / HWTILE), 256, 0, stream>>>(x, ws, bvec, out);
    finalize_kernel<<<1, 512, 0, stream>>>(out, bvec, k);
}